// Round 1
// baseline (1125.659 us; speedup 1.0000x reference)
//
#include <hip/hip_runtime.h>
#include <math.h>

#define NSLOPE 0.2f

// ---------------- CSR build ----------------

__global__ void hist_kernel(const int* __restrict__ dst, int* __restrict__ deg, int E) {
    int e = blockIdx.x * blockDim.x + threadIdx.x;
    if (e < E) atomicAdd(&deg[dst[e]], 1);
}

#define SCAN_B 1024
__global__ void scan1_kernel(const int* __restrict__ deg, int* __restrict__ incl,
                             int* __restrict__ bsums, int n) {
    __shared__ int sh[SCAN_B];
    int t = threadIdx.x;
    int g = blockIdx.x * SCAN_B + t;
    int v = (g < n) ? deg[g] : 0;
    sh[t] = v;
    __syncthreads();
    for (int d = 1; d < SCAN_B; d <<= 1) {
        int add = (t >= d) ? sh[t - d] : 0;
        __syncthreads();
        sh[t] += add;
        __syncthreads();
    }
    if (g < n) incl[g] = sh[t];
    if (t == SCAN_B - 1) bsums[blockIdx.x] = sh[t];
}

__global__ void scan2_kernel(int* bsums, int nb) {
    if (threadIdx.x == 0 && blockIdx.x == 0) {
        int acc = 0;
        for (int i = 0; i < nb; i++) { int v = bsums[i]; bsums[i] = acc; acc += v; }
    }
}

__global__ void scan3_kernel(const int* __restrict__ incl, const int* __restrict__ deg,
                             const int* __restrict__ bsums, int* __restrict__ rowstart,
                             int n, int E) {
    int g = blockIdx.x * SCAN_B + threadIdx.x;
    if (g < n) rowstart[g] = incl[g] - deg[g] + bsums[blockIdx.x];
    if (g == 0) rowstart[n] = E;
}

__global__ void scatter_kernel(const int* __restrict__ src, const int* __restrict__ dst,
                               const int* __restrict__ rowstart, int* __restrict__ cursor,
                               int* __restrict__ csr_src, int E) {
    int e = blockIdx.x * blockDim.x + threadIdx.x;
    if (e < E) {
        int d = dst[e];
        int pos = atomicAdd(&cursor[d], 1);
        csr_src[rowstart[d] + pos] = src[e];
    }
}

// ---------------- projection GEMM: xl = h@Wl, xr = h@Wr ----------------

template<int FIN, int FOUT, int RPT>
__global__ __launch_bounds__(256) void proj_kernel(
    const float* __restrict__ h, const float* __restrict__ Wl, const float* __restrict__ Wr,
    float* __restrict__ xl, float* __restrict__ xr, int n)
{
    constexpr int NG = 256 / FOUT;   // row groups per block
    constexpr int ROWS = NG * RPT;   // rows per block
    constexpr int KC = 64;           // k-chunk
    __shared__ float sWl[KC][FOUT];
    __shared__ float sWr[KC][FOUT];
    __shared__ float sx[ROWS][FIN];
    const int tid = threadIdx.x;
    const int row0 = blockIdx.x * ROWS;

    for (int i = tid; i < ROWS * FIN; i += 256) {
        int r = i / FIN, c = i % FIN;
        int gr = row0 + r;
        sx[r][c] = (gr < n) ? h[(size_t)gr * FIN + c] : 0.f;
    }

    const int f = tid % FOUT;
    const int g = tid / FOUT;
    float accl[RPT], accr[RPT];
#pragma unroll
    for (int r = 0; r < RPT; ++r) { accl[r] = 0.f; accr[r] = 0.f; }

    for (int kc = 0; kc < FIN; kc += KC) {
        __syncthreads();
        for (int i = tid; i < KC * FOUT; i += 256) {
            int kk = i / FOUT, ff = i % FOUT;
            sWl[kk][ff] = Wl[(size_t)(kc + kk) * FOUT + ff];
            sWr[kk][ff] = Wr[(size_t)(kc + kk) * FOUT + ff];
        }
        __syncthreads();
#pragma unroll 8
        for (int k = 0; k < KC; ++k) {
            float wl = sWl[k][f], wr = sWr[k][f];
#pragma unroll
            for (int r = 0; r < RPT; ++r) {
                float xv = sx[g * RPT + r][kc + k];
                accl[r] += xv * wl;
                accr[r] += xv * wr;
            }
        }
    }
#pragma unroll
    for (int r = 0; r < RPT; ++r) {
        int gr = row0 + g * RPT + r;
        if (gr < n) {
            xl[(size_t)gr * FOUT + f] = accl[r];
            xr[(size_t)gr * FOUT + f] = accr[r];
        }
    }
}

// ---------------- per-dst online-softmax aggregation ----------------
// AMODE: 1 = ELU(alpha=1), 2 = ELU(alpha=32)

template<int F, int AMODE>
__global__ __launch_bounds__(256) void agg_kernel(
    const float* __restrict__ xl, const float* __restrict__ xr, const float* __restrict__ att,
    const int* __restrict__ rowstart, const int* __restrict__ csr_src,
    float* __restrict__ out, int n)
{
    int wid = (blockIdx.x * blockDim.x + threadIdx.x) >> 6;
    int lane = threadIdx.x & 63;
    if (wid >= n) return;

    float xrv  = (lane < F) ? xr[(size_t)wid * F + lane] : 0.f;
    float attv = (lane < F) ? att[lane] : 0.f;
    int s0 = rowstart[wid], s1 = rowstart[wid + 1];

    float m = -INFINITY, ssum = 0.f, o = 0.f;
    for (int i = s0; i < s1; ++i) {
        int src = csr_src[i];
        float xv = (lane < F) ? xl[(size_t)src * F + lane] : 0.f;
        float e = xv + xrv;
        e = (e > 0.f) ? e : NSLOPE * e;
        float p = e * attv;
#pragma unroll
        for (int off = 32; off > 0; off >>= 1) p += __shfl_xor(p, off);
        if (p > m) {
            float c = __expf(m - p);
            ssum *= c; o *= c; m = p;
        }
        float w = __expf(p - m);
        ssum += w;
        o += w * xv;
    }
    float res = o / (ssum + 1e-16f);
    if (AMODE == 1) res = (res > 0.f) ? res : expm1f(res);
    else            res = (res > 0.f) ? res : 32.f * expm1f(res);
    if (lane < F) out[(size_t)wid * F + lane] = res;
}

// ---------------- launcher ----------------

extern "C" void kernel_launch(void* const* d_in, const int* in_sizes, int n_in,
                              void* d_out, int out_size, void* d_ws, size_t ws_size,
                              hipStream_t stream) {
    const float* x    = (const float*)d_in[0];
    const int*   ei   = (const int*)d_in[1];
    const float* Wl1  = (const float*)d_in[2];
    const float* Wr1  = (const float*)d_in[3];
    const float* att1 = (const float*)d_in[4];
    const float* Wl2  = (const float*)d_in[5];
    const float* Wr2  = (const float*)d_in[6];
    const float* att2 = (const float*)d_in[7];
    const float* Wl3  = (const float*)d_in[8];
    const float* Wr3  = (const float*)d_in[9];
    const float* att3 = (const float*)d_in[10];
    const float* Wl4  = (const float*)d_in[11];
    const float* Wr4  = (const float*)d_in[12];
    const float* att4 = (const float*)d_in[13];

    const int N = in_sizes[0] / 128;
    const int E = in_sizes[1] / 2;
    const int* src = ei;
    const int* dst = ei + E;

    char* w = (char*)d_ws;
    size_t off = 0;
    auto take = [&](size_t bytes) -> void* {
        void* p = w + off;
        off = (off + bytes + 255) & ~(size_t)255;
        return p;
    };
    int* deg      = (int*)take((size_t)N * 4);
    int* cursor   = (int*)take((size_t)N * 4);
    int* incl     = (int*)take((size_t)N * 4);
    int* bsums    = (int*)take(4096);
    int* rowstart = (int*)take((size_t)(N + 1) * 4);
    int* csr_src  = (int*)take((size_t)E * 4);
    float* xl = (float*)take((size_t)N * 64 * 4);
    float* xr = (float*)take((size_t)N * 64 * 4);
    float* hA = (float*)take((size_t)N * 64 * 4);
    float* hB = (float*)take((size_t)N * 64 * 4);
    float* outf = (float*)d_out;

    hipMemsetAsync(deg, 0, (size_t)N * 4, stream);
    hipMemsetAsync(cursor, 0, (size_t)N * 4, stream);

    int ebl = (E + 255) / 256;
    hist_kernel<<<ebl, 256, 0, stream>>>(dst, deg, E);

    int nsb = (N + SCAN_B - 1) / SCAN_B;
    scan1_kernel<<<nsb, SCAN_B, 0, stream>>>(deg, incl, bsums, N);
    scan2_kernel<<<1, 64, 0, stream>>>(bsums, nsb);
    scan3_kernel<<<nsb, SCAN_B, 0, stream>>>(incl, deg, bsums, rowstart, N, E);
    scatter_kernel<<<ebl, 256, 0, stream>>>(src, dst, rowstart, cursor, csr_src, E);

    int aggbl = (N * 64 + 255) / 256;   // one wave (64 lanes) per dst node

    // layer 1: 128 -> 64, ELU
    proj_kernel<128, 64, 8><<<(N + 31) / 32, 256, 0, stream>>>(x, Wl1, Wr1, xl, xr, N);
    agg_kernel<64, 1><<<aggbl, 256, 0, stream>>>(xl, xr, att1, rowstart, csr_src, hA, N);

    // layer 2: 64 -> 64, ELU
    proj_kernel<64, 64, 8><<<(N + 31) / 32, 256, 0, stream>>>(hA, Wl2, Wr2, xl, xr, N);
    agg_kernel<64, 1><<<aggbl, 256, 0, stream>>>(xl, xr, att2, rowstart, csr_src, hB, N);

    // layer 3: 64 -> 64, ELU
    proj_kernel<64, 64, 8><<<(N + 31) / 32, 256, 0, stream>>>(hB, Wl3, Wr3, xl, xr, N);
    agg_kernel<64, 1><<<aggbl, 256, 0, stream>>>(xl, xr, att3, rowstart, csr_src, hA, N);

    // layer 4: 64 -> 32, final quirky ELU (alpha = 32)
    proj_kernel<64, 32, 8><<<(N + 63) / 64, 256, 0, stream>>>(hA, Wl4, Wr4, xl, xr, N);
    agg_kernel<32, 2><<<aggbl, 256, 0, stream>>>(xl, xr, att4, rowstart, csr_src, outf, N);
}

// Round 2
// 631.485 us; speedup vs baseline: 1.7826x; 1.7826x over previous
//
#include <hip/hip_runtime.h>
#include <math.h>

#define NSLOPE 0.2f

// ---------------- CSR build ----------------

__global__ void hist_kernel(const int* __restrict__ dst, int* __restrict__ deg, int E) {
    int e = blockIdx.x * blockDim.x + threadIdx.x;
    if (e < E) atomicAdd(&deg[dst[e]], 1);
}

#define SCAN_B 1024
__global__ void scan1_kernel(const int* __restrict__ deg, int* __restrict__ incl,
                             int* __restrict__ bsums, int n) {
    __shared__ int sh[SCAN_B];
    int t = threadIdx.x;
    int g = blockIdx.x * SCAN_B + t;
    int v = (g < n) ? deg[g] : 0;
    sh[t] = v;
    __syncthreads();
    for (int d = 1; d < SCAN_B; d <<= 1) {
        int add = (t >= d) ? sh[t - d] : 0;
        __syncthreads();
        sh[t] += add;
        __syncthreads();
    }
    if (g < n) incl[g] = sh[t];
    if (t == SCAN_B - 1) bsums[blockIdx.x] = sh[t];
}

__global__ void scan2_kernel(int* bsums, int nb) {
    if (threadIdx.x == 0 && blockIdx.x == 0) {
        int acc = 0;
        for (int i = 0; i < nb; i++) { int v = bsums[i]; bsums[i] = acc; acc += v; }
    }
}

__global__ void scan3_kernel(const int* __restrict__ incl, const int* __restrict__ deg,
                             const int* __restrict__ bsums, int* __restrict__ rowstart,
                             int n, int E) {
    int g = blockIdx.x * SCAN_B + threadIdx.x;
    if (g < n) rowstart[g] = incl[g] - deg[g] + bsums[blockIdx.x];
    if (g == 0) rowstart[n] = E;
}

__global__ void scatter_kernel(const int* __restrict__ src, const int* __restrict__ dst,
                               const int* __restrict__ rowstart, int* __restrict__ cursor,
                               int* __restrict__ csr_src, int E) {
    int e = blockIdx.x * blockDim.x + threadIdx.x;
    if (e < E) {
        int d = dst[e];
        int pos = atomicAdd(&cursor[d], 1);
        csr_src[rowstart[d] + pos] = src[e];
    }
}

// ---------------- projection GEMM: xl = h@Wl, xr = h@Wr ----------------

template<int FIN, int FOUT, int RPT>
__global__ __launch_bounds__(256) void proj_kernel(
    const float* __restrict__ h, const float* __restrict__ Wl, const float* __restrict__ Wr,
    float* __restrict__ xl, float* __restrict__ xr, int n)
{
    constexpr int NG = 256 / FOUT;   // row groups per block
    constexpr int ROWS = NG * RPT;   // rows per block
    constexpr int KC = 64;           // k-chunk
    __shared__ float sWl[KC][FOUT];
    __shared__ float sWr[KC][FOUT];
    __shared__ float sx[ROWS][FIN];
    const int tid = threadIdx.x;
    const int row0 = blockIdx.x * ROWS;

    for (int i = tid; i < ROWS * FIN; i += 256) {
        int r = i / FIN, c = i % FIN;
        int gr = row0 + r;
        sx[r][c] = (gr < n) ? h[(size_t)gr * FIN + c] : 0.f;
    }

    const int f = tid % FOUT;
    const int g = tid / FOUT;
    float accl[RPT], accr[RPT];
#pragma unroll
    for (int r = 0; r < RPT; ++r) { accl[r] = 0.f; accr[r] = 0.f; }

    for (int kc = 0; kc < FIN; kc += KC) {
        __syncthreads();
        for (int i = tid; i < KC * FOUT; i += 256) {
            int kk = i / FOUT, ff = i % FOUT;
            sWl[kk][ff] = Wl[(size_t)(kc + kk) * FOUT + ff];
            sWr[kk][ff] = Wr[(size_t)(kc + kk) * FOUT + ff];
        }
        __syncthreads();
#pragma unroll 8
        for (int k = 0; k < KC; ++k) {
            float wl = sWl[k][f], wr = sWr[k][f];
#pragma unroll
            for (int r = 0; r < RPT; ++r) {
                float xv = sx[g * RPT + r][kc + k];
                accl[r] += xv * wl;
                accr[r] += xv * wr;
            }
        }
    }
#pragma unroll
    for (int r = 0; r < RPT; ++r) {
        int gr = row0 + g * RPT + r;
        if (gr < n) {
            xl[(size_t)gr * FOUT + f] = accl[r];
            xr[(size_t)gr * FOUT + f] = accr[r];
        }
    }
}

// ---------------- per-dst online-softmax aggregation ----------------
// One wave per dst node. Each lane holds 4 features (float4); an edge spans
// LPE = F/4 lanes; GRP = 64/LPE edges are processed per iteration.
// AMODE: 1 = ELU(alpha=1), 2 = ELU(alpha=32)

template<int F, int AMODE>
__global__ __launch_bounds__(256) void agg_kernel(
    const float* __restrict__ xl, const float* __restrict__ xr, const float* __restrict__ att,
    const int* __restrict__ rowstart, const int* __restrict__ csr_src,
    float* __restrict__ out, int n)
{
    constexpr int LPE = F / 4;      // lanes per edge
    constexpr int GRP = 64 / LPE;   // edges in flight per iteration

    int wid = (blockIdx.x * blockDim.x + threadIdx.x) >> 6;
    int lane = threadIdx.x & 63;
    if (wid >= n) return;
    int grp = lane / LPE;
    int fl  = lane % LPE;

    float4 xrv  = *(const float4*)&xr[(size_t)wid * F + fl * 4];
    float4 attv = *(const float4*)&att[fl * 4];

    int s0 = rowstart[wid], s1 = rowstart[wid + 1];
    int deg = s1 - s0;
    int niter = (deg + GRP - 1) / GRP;

    float m = -INFINITY, ssum = 0.f;
    float o0 = 0.f, o1 = 0.f, o2 = 0.f, o3 = 0.f;

    // software-pipelined src-index fetch
    int idx = s0 + grp;
    bool valid = idx < s1;
    int sv = valid ? csr_src[idx] : 0;

    for (int it = 0; it < niter; ++it) {
        float4 xv = *(const float4*)&xl[(size_t)sv * F + fl * 4];

        // prefetch next src index
        int nidx = idx + GRP;
        bool nvalid = nidx < s1;
        int nsv = nvalid ? csr_src[nidx] : 0;

        float e0 = xv.x + xrv.x; e0 = (e0 > 0.f) ? e0 : NSLOPE * e0;
        float e1 = xv.y + xrv.y; e1 = (e1 > 0.f) ? e1 : NSLOPE * e1;
        float e2 = xv.z + xrv.z; e2 = (e2 > 0.f) ? e2 : NSLOPE * e2;
        float e3 = xv.w + xrv.w; e3 = (e3 > 0.f) ? e3 : NSLOPE * e3;
        float p = e0 * attv.x + e1 * attv.y + e2 * attv.z + e3 * attv.w;
        // reduce within the LPE lanes of this edge
#pragma unroll
        for (int off = 1; off < LPE; off <<= 1) p += __shfl_xor(p, off);

        if (valid) {
            if (p > m) {
                float c = __expf(m - p);
                ssum *= c; o0 *= c; o1 *= c; o2 *= c; o3 *= c;
                m = p;
            }
            float w = __expf(p - m);
            ssum += w;
            o0 += w * xv.x; o1 += w * xv.y; o2 += w * xv.z; o3 += w * xv.w;
        }
        idx = nidx; valid = nvalid; sv = nsv;
    }

    // merge the GRP per-group online-softmax states
#pragma unroll
    for (int off = LPE; off < 64; off <<= 1) {
        float m2 = __shfl_xor(m, off);
        float s2 = __shfl_xor(ssum, off);
        float q0 = __shfl_xor(o0, off);
        float q1 = __shfl_xor(o1, off);
        float q2 = __shfl_xor(o2, off);
        float q3 = __shfl_xor(o3, off);
        float M = fmaxf(m, m2);
        float ca = (m  > -INFINITY) ? __expf(m - M) : 0.f;
        float cb = (m2 > -INFINITY) ? __expf(m2 - M) : 0.f;
        ssum = ssum * ca + s2 * cb;
        o0 = o0 * ca + q0 * cb;
        o1 = o1 * ca + q1 * cb;
        o2 = o2 * ca + q2 * cb;
        o3 = o3 * ca + q3 * cb;
        m = M;
    }

    float inv = 1.f / (ssum + 1e-16f);
    float4 res;
    res.x = o0 * inv; res.y = o1 * inv; res.z = o2 * inv; res.w = o3 * inv;
    if (AMODE == 1) {
        res.x = (res.x > 0.f) ? res.x : expm1f(res.x);
        res.y = (res.y > 0.f) ? res.y : expm1f(res.y);
        res.z = (res.z > 0.f) ? res.z : expm1f(res.z);
        res.w = (res.w > 0.f) ? res.w : expm1f(res.w);
    } else {
        res.x = (res.x > 0.f) ? res.x : 32.f * expm1f(res.x);
        res.y = (res.y > 0.f) ? res.y : 32.f * expm1f(res.y);
        res.z = (res.z > 0.f) ? res.z : 32.f * expm1f(res.z);
        res.w = (res.w > 0.f) ? res.w : 32.f * expm1f(res.w);
    }
    if (grp == 0) *(float4*)&out[(size_t)wid * F + fl * 4] = res;
}

// ---------------- launcher ----------------

extern "C" void kernel_launch(void* const* d_in, const int* in_sizes, int n_in,
                              void* d_out, int out_size, void* d_ws, size_t ws_size,
                              hipStream_t stream) {
    const float* x    = (const float*)d_in[0];
    const int*   ei   = (const int*)d_in[1];
    const float* Wl1  = (const float*)d_in[2];
    const float* Wr1  = (const float*)d_in[3];
    const float* att1 = (const float*)d_in[4];
    const float* Wl2  = (const float*)d_in[5];
    const float* Wr2  = (const float*)d_in[6];
    const float* att2 = (const float*)d_in[7];
    const float* Wl3  = (const float*)d_in[8];
    const float* Wr3  = (const float*)d_in[9];
    const float* att3 = (const float*)d_in[10];
    const float* Wl4  = (const float*)d_in[11];
    const float* Wr4  = (const float*)d_in[12];
    const float* att4 = (const float*)d_in[13];

    const int N = in_sizes[0] / 128;
    const int E = in_sizes[1] / 2;
    const int* src = ei;
    const int* dst = ei + E;

    char* w = (char*)d_ws;
    size_t off = 0;
    auto take = [&](size_t bytes) -> void* {
        void* p = w + off;
        off = (off + bytes + 255) & ~(size_t)255;
        return p;
    };
    int* deg      = (int*)take((size_t)N * 4);
    int* cursor   = (int*)take((size_t)N * 4);
    int* incl     = (int*)take((size_t)N * 4);
    int* bsums    = (int*)take(4096);
    int* rowstart = (int*)take((size_t)(N + 1) * 4);
    int* csr_src  = (int*)take((size_t)E * 4);
    float* xl = (float*)take((size_t)N * 64 * 4);
    float* xr = (float*)take((size_t)N * 64 * 4);
    float* hA = (float*)take((size_t)N * 64 * 4);
    float* hB = (float*)take((size_t)N * 64 * 4);
    float* outf = (float*)d_out;

    hipMemsetAsync(deg, 0, (size_t)N * 4, stream);
    hipMemsetAsync(cursor, 0, (size_t)N * 4, stream);

    int ebl = (E + 255) / 256;
    hist_kernel<<<ebl, 256, 0, stream>>>(dst, deg, E);

    int nsb = (N + SCAN_B - 1) / SCAN_B;
    scan1_kernel<<<nsb, SCAN_B, 0, stream>>>(deg, incl, bsums, N);
    scan2_kernel<<<1, 64, 0, stream>>>(bsums, nsb);
    scan3_kernel<<<nsb, SCAN_B, 0, stream>>>(incl, deg, bsums, rowstart, N, E);
    scatter_kernel<<<ebl, 256, 0, stream>>>(src, dst, rowstart, cursor, csr_src, E);

    int aggbl = (N * 64 + 255) / 256;   // one wave (64 lanes) per dst node

    // layer 1: 128 -> 64, ELU
    proj_kernel<128, 64, 8><<<(N + 31) / 32, 256, 0, stream>>>(x, Wl1, Wr1, xl, xr, N);
    agg_kernel<64, 1><<<aggbl, 256, 0, stream>>>(xl, xr, att1, rowstart, csr_src, hA, N);

    // layer 2: 64 -> 64, ELU
    proj_kernel<64, 64, 8><<<(N + 31) / 32, 256, 0, stream>>>(hA, Wl2, Wr2, xl, xr, N);
    agg_kernel<64, 1><<<aggbl, 256, 0, stream>>>(xl, xr, att2, rowstart, csr_src, hB, N);

    // layer 3: 64 -> 64, ELU
    proj_kernel<64, 64, 8><<<(N + 31) / 32, 256, 0, stream>>>(hB, Wl3, Wr3, xl, xr, N);
    agg_kernel<64, 1><<<aggbl, 256, 0, stream>>>(xl, xr, att3, rowstart, csr_src, hA, N);

    // layer 4: 64 -> 32, final quirky ELU (alpha = 32)
    proj_kernel<64, 32, 8><<<(N + 63) / 64, 256, 0, stream>>>(hA, Wl4, Wr4, xl, xr, N);
    agg_kernel<32, 2><<<aggbl, 256, 0, stream>>>(xl, xr, att4, rowstart, csr_src, outf, N);
}

// Round 3
// 600.356 us; speedup vs baseline: 1.8750x; 1.0519x over previous
//
#include <hip/hip_runtime.h>
#include <math.h>

#define NSLOPE 0.2f

// ---------------- CSR build ----------------

__global__ void hist_kernel(const int* __restrict__ dst, int* __restrict__ deg, int E) {
    int e = blockIdx.x * blockDim.x + threadIdx.x;
    if (e < E) atomicAdd(&deg[dst[e]], 1);
}

#define SCAN_B 1024
__global__ void scan1_kernel(const int* __restrict__ deg, int* __restrict__ incl,
                             int* __restrict__ bsums, int n) {
    __shared__ int sh[SCAN_B];
    int t = threadIdx.x;
    int g = blockIdx.x * SCAN_B + t;
    int v = (g < n) ? deg[g] : 0;
    sh[t] = v;
    __syncthreads();
    for (int d = 1; d < SCAN_B; d <<= 1) {
        int add = (t >= d) ? sh[t - d] : 0;
        __syncthreads();
        sh[t] += add;
        __syncthreads();
    }
    if (g < n) incl[g] = sh[t];
    if (t == SCAN_B - 1) bsums[blockIdx.x] = sh[t];
}

// 1-block parallel exclusive scan of up to 1024 block sums
__global__ void scan2_kernel(int* bsums, int nb) {
    __shared__ int sh[1024];
    int t = threadIdx.x;
    int v = (t < nb) ? bsums[t] : 0;
    sh[t] = v;
    __syncthreads();
    for (int d = 1; d < 1024; d <<= 1) {
        int add = (t >= d) ? sh[t - d] : 0;
        __syncthreads();
        sh[t] += add;
        __syncthreads();
    }
    if (t < nb) bsums[t] = sh[t] - v;   // exclusive
}

__global__ void scan3_kernel(const int* __restrict__ incl, const int* __restrict__ deg,
                             const int* __restrict__ bsums, int* __restrict__ rowstart,
                             int n, int E) {
    int g = blockIdx.x * SCAN_B + threadIdx.x;
    if (g < n) rowstart[g] = incl[g] - deg[g] + bsums[blockIdx.x];
    if (g == 0) rowstart[n] = E;
}

// XCD-partitioned scatter: block b handles partition p = b%8 (dst range) and
// edge chunk b/8. All writes to a given csr_src region come from one XCD ->
// no cross-XCD L2 line thrash on the random 4B scatter writes.
#define NXCD 8
#define SCAT_CHUNK 16384
__global__ __launch_bounds__(256) void scatter_kernel(
    const int* __restrict__ src, const int* __restrict__ dst,
    const int* __restrict__ rowstart, int* __restrict__ cursor,
    int* __restrict__ csr_src, int E, int np)
{
    int p  = blockIdx.x % NXCD;        // partition (and, heuristically, XCD)
    int c  = blockIdx.x / NXCD;        // edge chunk
    int lo = p * np, hi = lo + np;
    int e0 = c * SCAT_CHUNK;
    int e1 = min(e0 + SCAT_CHUNK, E);
    for (int e = e0 + (int)threadIdx.x; e < e1; e += 256) {
        int d = dst[e];
        int s = src[e];
        if (d >= lo && d < hi) {
            int pos = atomicAdd(&cursor[d], 1);
            csr_src[rowstart[d] + pos] = s;
        }
    }
}

// ---------------- projection GEMM: xl = h@Wl, xr = h@Wr ----------------

template<int FIN, int FOUT, int RPT>
__global__ __launch_bounds__(256) void proj_kernel(
    const float* __restrict__ h, const float* __restrict__ Wl, const float* __restrict__ Wr,
    float* __restrict__ xl, float* __restrict__ xr, int n)
{
    constexpr int NG = 256 / FOUT;   // row groups per block
    constexpr int ROWS = NG * RPT;   // rows per block
    constexpr int KC = 64;           // k-chunk
    __shared__ float sWl[KC][FOUT];
    __shared__ float sWr[KC][FOUT];
    __shared__ float sx[ROWS][FIN];
    const int tid = threadIdx.x;
    const int row0 = blockIdx.x * ROWS;

    for (int i = tid; i < ROWS * FIN; i += 256) {
        int r = i / FIN, c = i % FIN;
        int gr = row0 + r;
        sx[r][c] = (gr < n) ? h[(size_t)gr * FIN + c] : 0.f;
    }

    const int f = tid % FOUT;
    const int g = tid / FOUT;
    float accl[RPT], accr[RPT];
#pragma unroll
    for (int r = 0; r < RPT; ++r) { accl[r] = 0.f; accr[r] = 0.f; }

    for (int kc = 0; kc < FIN; kc += KC) {
        __syncthreads();
        for (int i = tid; i < KC * FOUT; i += 256) {
            int kk = i / FOUT, ff = i % FOUT;
            sWl[kk][ff] = Wl[(size_t)(kc + kk) * FOUT + ff];
            sWr[kk][ff] = Wr[(size_t)(kc + kk) * FOUT + ff];
        }
        __syncthreads();
#pragma unroll 8
        for (int k = 0; k < KC; ++k) {
            float wl = sWl[k][f], wr = sWr[k][f];
#pragma unroll
            for (int r = 0; r < RPT; ++r) {
                float xv = sx[g * RPT + r][kc + k];
                accl[r] += xv * wl;
                accr[r] += xv * wr;
            }
        }
    }
#pragma unroll
    for (int r = 0; r < RPT; ++r) {
        int gr = row0 + g * RPT + r;
        if (gr < n) {
            xl[(size_t)gr * FOUT + f] = accl[r];
            xr[(size_t)gr * FOUT + f] = accr[r];
        }
    }
}

// ---------------- per-dst online-softmax aggregation ----------------
// One wave per dst node. Each lane holds 4 features (float4); an edge spans
// LPE = F/4 lanes; GRP = 64/LPE edges are processed per iteration.
// AMODE: 1 = ELU(alpha=1), 2 = ELU(alpha=32)

template<int F, int AMODE>
__global__ __launch_bounds__(256) void agg_kernel(
    const float* __restrict__ xl, const float* __restrict__ xr, const float* __restrict__ att,
    const int* __restrict__ rowstart, const int* __restrict__ csr_src,
    float* __restrict__ out, int n)
{
    constexpr int LPE = F / 4;      // lanes per edge
    constexpr int GRP = 64 / LPE;   // edges in flight per iteration

    int wid = (blockIdx.x * blockDim.x + threadIdx.x) >> 6;
    int lane = threadIdx.x & 63;
    if (wid >= n) return;
    int grp = lane / LPE;
    int fl  = lane % LPE;

    float4 xrv  = *(const float4*)&xr[(size_t)wid * F + fl * 4];
    float4 attv = *(const float4*)&att[fl * 4];

    int s0 = rowstart[wid], s1 = rowstart[wid + 1];
    int deg = s1 - s0;
    int niter = (deg + GRP - 1) / GRP;

    float m = -INFINITY, ssum = 0.f;
    float o0 = 0.f, o1 = 0.f, o2 = 0.f, o3 = 0.f;

    // software-pipelined src-index fetch
    int idx = s0 + grp;
    bool valid = idx < s1;
    int sv = valid ? csr_src[idx] : 0;

    for (int it = 0; it < niter; ++it) {
        float4 xv = *(const float4*)&xl[(size_t)sv * F + fl * 4];

        // prefetch next src index
        int nidx = idx + GRP;
        bool nvalid = nidx < s1;
        int nsv = nvalid ? csr_src[nidx] : 0;

        float e0 = xv.x + xrv.x; e0 = (e0 > 0.f) ? e0 : NSLOPE * e0;
        float e1 = xv.y + xrv.y; e1 = (e1 > 0.f) ? e1 : NSLOPE * e1;
        float e2 = xv.z + xrv.z; e2 = (e2 > 0.f) ? e2 : NSLOPE * e2;
        float e3 = xv.w + xrv.w; e3 = (e3 > 0.f) ? e3 : NSLOPE * e3;
        float p = e0 * attv.x + e1 * attv.y + e2 * attv.z + e3 * attv.w;
        // reduce within the LPE lanes of this edge
#pragma unroll
        for (int off = 1; off < LPE; off <<= 1) p += __shfl_xor(p, off);

        if (valid) {
            if (p > m) {
                float c = __expf(m - p);
                ssum *= c; o0 *= c; o1 *= c; o2 *= c; o3 *= c;
                m = p;
            }
            float w = __expf(p - m);
            ssum += w;
            o0 += w * xv.x; o1 += w * xv.y; o2 += w * xv.z; o3 += w * xv.w;
        }
        idx = nidx; valid = nvalid; sv = nsv;
    }

    // merge the GRP per-group online-softmax states
#pragma unroll
    for (int off = LPE; off < 64; off <<= 1) {
        float m2 = __shfl_xor(m, off);
        float s2 = __shfl_xor(ssum, off);
        float q0 = __shfl_xor(o0, off);
        float q1 = __shfl_xor(o1, off);
        float q2 = __shfl_xor(o2, off);
        float q3 = __shfl_xor(o3, off);
        float M = fmaxf(m, m2);
        float ca = (m  > -INFINITY) ? __expf(m - M) : 0.f;
        float cb = (m2 > -INFINITY) ? __expf(m2 - M) : 0.f;
        ssum = ssum * ca + s2 * cb;
        o0 = o0 * ca + q0 * cb;
        o1 = o1 * ca + q1 * cb;
        o2 = o2 * ca + q2 * cb;
        o3 = o3 * ca + q3 * cb;
        m = M;
    }

    float inv = 1.f / (ssum + 1e-16f);
    float4 res;
    res.x = o0 * inv; res.y = o1 * inv; res.z = o2 * inv; res.w = o3 * inv;
    if (AMODE == 1) {
        res.x = (res.x > 0.f) ? res.x : expm1f(res.x);
        res.y = (res.y > 0.f) ? res.y : expm1f(res.y);
        res.z = (res.z > 0.f) ? res.z : expm1f(res.z);
        res.w = (res.w > 0.f) ? res.w : expm1f(res.w);
    } else {
        res.x = (res.x > 0.f) ? res.x : 32.f * expm1f(res.x);
        res.y = (res.y > 0.f) ? res.y : 32.f * expm1f(res.y);
        res.z = (res.z > 0.f) ? res.z : 32.f * expm1f(res.z);
        res.w = (res.w > 0.f) ? res.w : 32.f * expm1f(res.w);
    }
    if (grp == 0) *(float4*)&out[(size_t)wid * F + fl * 4] = res;
}

// ---------------- launcher ----------------

extern "C" void kernel_launch(void* const* d_in, const int* in_sizes, int n_in,
                              void* d_out, int out_size, void* d_ws, size_t ws_size,
                              hipStream_t stream) {
    const float* x    = (const float*)d_in[0];
    const int*   ei   = (const int*)d_in[1];
    const float* Wl1  = (const float*)d_in[2];
    const float* Wr1  = (const float*)d_in[3];
    const float* att1 = (const float*)d_in[4];
    const float* Wl2  = (const float*)d_in[5];
    const float* Wr2  = (const float*)d_in[6];
    const float* att2 = (const float*)d_in[7];
    const float* Wl3  = (const float*)d_in[8];
    const float* Wr3  = (const float*)d_in[9];
    const float* att3 = (const float*)d_in[10];
    const float* Wl4  = (const float*)d_in[11];
    const float* Wr4  = (const float*)d_in[12];
    const float* att4 = (const float*)d_in[13];

    const int N = in_sizes[0] / 128;
    const int E = in_sizes[1] / 2;
    const int* src = ei;
    const int* dst = ei + E;

    char* w = (char*)d_ws;
    size_t off = 0;
    auto take = [&](size_t bytes) -> void* {
        void* p = w + off;
        off = (off + bytes + 255) & ~(size_t)255;
        return p;
    };
    int* deg      = (int*)take((size_t)N * 4);
    int* cursor   = (int*)take((size_t)N * 4);
    int* incl     = (int*)take((size_t)N * 4);
    int* bsums    = (int*)take(4096);
    int* rowstart = (int*)take((size_t)(N + 1) * 4);
    int* csr_src  = (int*)take((size_t)E * 4);
    float* xl = (float*)take((size_t)N * 64 * 4);
    float* xr = (float*)take((size_t)N * 64 * 4);
    float* hA = (float*)take((size_t)N * 64 * 4);
    float* hB = (float*)take((size_t)N * 64 * 4);
    float* outf = (float*)d_out;

    hipMemsetAsync(deg, 0, (size_t)N * 4, stream);
    hipMemsetAsync(cursor, 0, (size_t)N * 4, stream);

    int ebl = (E + 255) / 256;
    hist_kernel<<<ebl, 256, 0, stream>>>(dst, deg, E);

    int nsb = (N + SCAN_B - 1) / SCAN_B;
    scan1_kernel<<<nsb, SCAN_B, 0, stream>>>(deg, incl, bsums, N);
    scan2_kernel<<<1, 1024, 0, stream>>>(bsums, nsb);
    scan3_kernel<<<nsb, SCAN_B, 0, stream>>>(incl, deg, bsums, rowstart, N, E);

    int np = (N + NXCD - 1) / NXCD;
    int nchunk = (E + SCAT_CHUNK - 1) / SCAT_CHUNK;
    scatter_kernel<<<nchunk * NXCD, 256, 0, stream>>>(src, dst, rowstart, cursor, csr_src, E, np);

    int aggbl = (N * 64 + 255) / 256;   // one wave (64 lanes) per dst node

    // layer 1: 128 -> 64, ELU
    proj_kernel<128, 64, 8><<<(N + 31) / 32, 256, 0, stream>>>(x, Wl1, Wr1, xl, xr, N);
    agg_kernel<64, 1><<<aggbl, 256, 0, stream>>>(xl, xr, att1, rowstart, csr_src, hA, N);

    // layer 2: 64 -> 64, ELU
    proj_kernel<64, 64, 8><<<(N + 31) / 32, 256, 0, stream>>>(hA, Wl2, Wr2, xl, xr, N);
    agg_kernel<64, 1><<<aggbl, 256, 0, stream>>>(xl, xr, att2, rowstart, csr_src, hB, N);

    // layer 3: 64 -> 64, ELU
    proj_kernel<64, 64, 8><<<(N + 31) / 32, 256, 0, stream>>>(hB, Wl3, Wr3, xl, xr, N);
    agg_kernel<64, 1><<<aggbl, 256, 0, stream>>>(xl, xr, att3, rowstart, csr_src, hA, N);

    // layer 4: 64 -> 32, final quirky ELU (alpha = 32)
    proj_kernel<64, 32, 8><<<(N + 63) / 64, 256, 0, stream>>>(hA, Wl4, Wr4, xl, xr, N);
    agg_kernel<32, 2><<<aggbl, 256, 0, stream>>>(xl, xr, att4, rowstart, csr_src, outf, N);
}

// Round 4
// 500.098 us; speedup vs baseline: 2.2509x; 1.2005x over previous
//
#include <hip/hip_runtime.h>
#include <math.h>

#define NSLOPE 0.2f

typedef __attribute__((ext_vector_type(8))) short bf16x8;
typedef __attribute__((ext_vector_type(4))) float f32x4;

__device__ inline unsigned short f32_to_bf16_bits(float f) {
    unsigned int u = __float_as_uint(f);
    unsigned int r = (u + 0x7fffu + ((u >> 16) & 1u)) >> 16;   // RNE
    return (unsigned short)r;
}
__device__ inline float bf16_bits_to_f32(unsigned short h) {
    return __uint_as_float(((unsigned int)h) << 16);
}

// ---------------- CSR build ----------------

__global__ void hist_kernel(const int* __restrict__ dst, int* __restrict__ deg, int E) {
    int e = blockIdx.x * blockDim.x + threadIdx.x;
    if (e < E) atomicAdd(&deg[dst[e]], 1);
}

#define SCAN_B 1024
__global__ void scan1_kernel(const int* __restrict__ deg, int* __restrict__ incl,
                             int* __restrict__ bsums, int n) {
    __shared__ int sh[SCAN_B];
    int t = threadIdx.x;
    int g = blockIdx.x * SCAN_B + t;
    int v = (g < n) ? deg[g] : 0;
    sh[t] = v;
    __syncthreads();
    for (int d = 1; d < SCAN_B; d <<= 1) {
        int add = (t >= d) ? sh[t - d] : 0;
        __syncthreads();
        sh[t] += add;
        __syncthreads();
    }
    if (g < n) incl[g] = sh[t];
    if (t == SCAN_B - 1) bsums[blockIdx.x] = sh[t];
}

// 1-block parallel exclusive scan of up to 1024 block sums
__global__ void scan2_kernel(int* bsums, int nb) {
    __shared__ int sh[1024];
    int t = threadIdx.x;
    int v = (t < nb) ? bsums[t] : 0;
    sh[t] = v;
    __syncthreads();
    for (int d = 1; d < 1024; d <<= 1) {
        int add = (t >= d) ? sh[t - d] : 0;
        __syncthreads();
        sh[t] += add;
        __syncthreads();
    }
    if (t < nb) bsums[t] = sh[t] - v;   // exclusive
}

__global__ void scan3_kernel(const int* __restrict__ incl, const int* __restrict__ deg,
                             const int* __restrict__ bsums, int* __restrict__ rowstart,
                             int n, int E) {
    int g = blockIdx.x * SCAN_B + threadIdx.x;
    if (g < n) rowstart[g] = incl[g] - deg[g] + bsums[blockIdx.x];
    if (g == 0) rowstart[n] = E;
}

// XCD-partitioned scatter (see round 3): block b -> partition b%8, chunk b/8.
#define NXCD 8
#define SCAT_CHUNK 16384
__global__ __launch_bounds__(256) void scatter_kernel(
    const int* __restrict__ src, const int* __restrict__ dst,
    const int* __restrict__ rowstart, int* __restrict__ cursor,
    int* __restrict__ csr_src, int E, int np)
{
    int p  = blockIdx.x % NXCD;
    int c  = blockIdx.x / NXCD;
    int lo = p * np, hi = lo + np;
    int e0 = c * SCAT_CHUNK;
    int e1 = min(e0 + SCAT_CHUNK, E);
    for (int e = e0 + (int)threadIdx.x; e < e1; e += 256) {
        int d = dst[e];
        int s = src[e];
        if (d >= lo && d < hi) {
            int pos = atomicAdd(&cursor[d], 1);
            csr_src[rowstart[d] + pos] = s;
        }
    }
}

// ---------------- weight prepack: W[FIN][FOUT] f32 -> hi/lo bf16 B-fragments ----------------
// B-frag layout for mfma_f32_16x16x32_bf16: lane holds B[k][col] with
// col = t*16 + (lane&15), k = ks*32 + (lane>>4)*8 + j, j=0..7.
// packed[part][((t*NK+ks)*64+lane)*8+j], part 0 = hi, part 1 = lo.

__global__ void prepack_kernel(const float* __restrict__ Wl, const float* __restrict__ Wr,
                               unsigned short* __restrict__ pWl, unsigned short* __restrict__ pWr,
                               int FIN, int FOUT) {
    int NT = FOUT >> 4, NK = FIN >> 5;
    int part = NT * NK * 512;   // ushorts per part
    int i = blockIdx.x * blockDim.x + threadIdx.x;
    int m = i / part;           // 0 = Wl, 1 = Wr
    if (m >= 2) return;
    int ii = i - m * part;
    int j = ii & 7;
    int lane = (ii >> 3) & 63;
    int rest = ii >> 9;
    int ks = rest % NK;
    int t = rest / NK;
    int k = ks * 32 + (lane >> 4) * 8 + j;
    int c = t * 16 + (lane & 15);
    const float* W = m ? Wr : Wl;
    unsigned short* P = m ? pWr : pWl;
    float w = W[(size_t)k * FOUT + c];
    unsigned short hi = f32_to_bf16_bits(w);
    unsigned short lo = f32_to_bf16_bits(w - bf16_bits_to_f32(hi));
    P[ii] = hi;
    P[part + ii] = lo;
}

// ---------------- MFMA projection: xl = x@Wl, xr = x@Wr (hi/lo split) ----------------
// Block = 4 waves; wave w owns rows blockIdx*64 + w*16 .. +15.
// A-frag: lane holds x[row0+(lane&15)][ks*32+(lane>>4)*8+j], split to bf16 hi/lo.
// 3-product split per tile: Ah*Bh + Ah*Bl + Al*Bh  (error ~2^-18, f32 accum).

template<int FIN, int FOUT>
__global__ __launch_bounds__(256) void proj_mfma_kernel(
    const float* __restrict__ x,
    const unsigned short* __restrict__ pWl, const unsigned short* __restrict__ pWr,
    float* __restrict__ xl, float* __restrict__ xr, int n)
{
    constexpr int NT = FOUT >> 4;
    constexpr int NK = FIN >> 5;
    constexpr int PART = NT * NK * 512;
    const int wave = threadIdx.x >> 6;
    const int lane = threadIdx.x & 63;
    const int row0 = blockIdx.x * 64 + wave * 16;
    int arow = row0 + (lane & 15);
    if (arow >= n) arow = n - 1;
    const int khalf = lane >> 4;

    f32x4 accl[NT], accr[NT];
#pragma unroll
    for (int t = 0; t < NT; ++t) {
        accl[t] = (f32x4){0.f, 0.f, 0.f, 0.f};
        accr[t] = (f32x4){0.f, 0.f, 0.f, 0.f};
    }

    const float* xrow = x + (size_t)arow * FIN + khalf * 8;
#pragma unroll
    for (int ks = 0; ks < NK; ++ks) {
        float4 a0 = *(const float4*)(xrow + ks * 32);
        float4 a1 = *(const float4*)(xrow + ks * 32 + 4);
        float av[8] = {a0.x, a0.y, a0.z, a0.w, a1.x, a1.y, a1.z, a1.w};
        bf16x8 ah, al;
#pragma unroll
        for (int j = 0; j < 8; ++j) {
            unsigned short h = f32_to_bf16_bits(av[j]);
            ah[j] = (short)h;
            al[j] = (short)f32_to_bf16_bits(av[j] - bf16_bits_to_f32(h));
        }
#pragma unroll
        for (int t = 0; t < NT; ++t) {
            const unsigned short* bpl = pWl + ((size_t)(t * NK + ks) * 64 + lane) * 8;
            bf16x8 bh  = *(const bf16x8*)bpl;
            bf16x8 blo = *(const bf16x8*)(bpl + PART);
            accl[t] = __builtin_amdgcn_mfma_f32_16x16x32_bf16(ah, bh,  accl[t], 0, 0, 0);
            accl[t] = __builtin_amdgcn_mfma_f32_16x16x32_bf16(ah, blo, accl[t], 0, 0, 0);
            accl[t] = __builtin_amdgcn_mfma_f32_16x16x32_bf16(al, bh,  accl[t], 0, 0, 0);
            const unsigned short* bpr = pWr + ((size_t)(t * NK + ks) * 64 + lane) * 8;
            bh  = *(const bf16x8*)bpr;
            blo = *(const bf16x8*)(bpr + PART);
            accr[t] = __builtin_amdgcn_mfma_f32_16x16x32_bf16(ah, bh,  accr[t], 0, 0, 0);
            accr[t] = __builtin_amdgcn_mfma_f32_16x16x32_bf16(ah, blo, accr[t], 0, 0, 0);
            accr[t] = __builtin_amdgcn_mfma_f32_16x16x32_bf16(al, bh,  accr[t], 0, 0, 0);
        }
    }
    // C/D layout: col = t*16 + (lane&15), row = row0 + (lane>>4)*4 + r
    const int orow0 = row0 + khalf * 4;
    const int colb = lane & 15;
#pragma unroll
    for (int t = 0; t < NT; ++t) {
        int col = t * 16 + colb;
#pragma unroll
        for (int r = 0; r < 4; ++r) {
            int rr = orow0 + r;
            if (rr < n) {
                xl[(size_t)rr * FOUT + col] = accl[t][r];
                xr[(size_t)rr * FOUT + col] = accr[t][r];
            }
        }
    }
}

// ---------------- per-dst online-softmax aggregation ----------------
// One wave per dst node; lane holds 4 features; LPE = F/4 lanes per edge,
// GRP = 64/LPE edges in flight. AMODE: 1 = ELU(1), 2 = ELU(32).

template<int F, int AMODE>
__global__ __launch_bounds__(256) void agg_kernel(
    const float* __restrict__ xl, const float* __restrict__ xr, const float* __restrict__ att,
    const int* __restrict__ rowstart, const int* __restrict__ csr_src,
    float* __restrict__ out, int n)
{
    constexpr int LPE = F / 4;
    constexpr int GRP = 64 / LPE;

    int wid = (blockIdx.x * blockDim.x + threadIdx.x) >> 6;
    int lane = threadIdx.x & 63;
    if (wid >= n) return;
    int grp = lane / LPE;
    int fl  = lane % LPE;

    float4 xrv  = *(const float4*)&xr[(size_t)wid * F + fl * 4];
    float4 attv = *(const float4*)&att[fl * 4];

    int s0 = rowstart[wid], s1 = rowstart[wid + 1];
    int deg = s1 - s0;
    int niter = (deg + GRP - 1) / GRP;

    float m = -INFINITY, ssum = 0.f;
    float o0 = 0.f, o1 = 0.f, o2 = 0.f, o3 = 0.f;

    int idx = s0 + grp;
    bool valid = idx < s1;
    int sv = valid ? csr_src[idx] : 0;

    for (int it = 0; it < niter; ++it) {
        float4 xv = *(const float4*)&xl[(size_t)sv * F + fl * 4];

        int nidx = idx + GRP;
        bool nvalid = nidx < s1;
        int nsv = nvalid ? csr_src[nidx] : 0;

        float e0 = xv.x + xrv.x; e0 = (e0 > 0.f) ? e0 : NSLOPE * e0;
        float e1 = xv.y + xrv.y; e1 = (e1 > 0.f) ? e1 : NSLOPE * e1;
        float e2 = xv.z + xrv.z; e2 = (e2 > 0.f) ? e2 : NSLOPE * e2;
        float e3 = xv.w + xrv.w; e3 = (e3 > 0.f) ? e3 : NSLOPE * e3;
        float p = e0 * attv.x + e1 * attv.y + e2 * attv.z + e3 * attv.w;
#pragma unroll
        for (int off = 1; off < LPE; off <<= 1) p += __shfl_xor(p, off);

        if (valid) {
            if (p > m) {
                float c = __expf(m - p);
                ssum *= c; o0 *= c; o1 *= c; o2 *= c; o3 *= c;
                m = p;
            }
            float w = __expf(p - m);
            ssum += w;
            o0 += w * xv.x; o1 += w * xv.y; o2 += w * xv.z; o3 += w * xv.w;
        }
        idx = nidx; valid = nvalid; sv = nsv;
    }

#pragma unroll
    for (int off = LPE; off < 64; off <<= 1) {
        float m2 = __shfl_xor(m, off);
        float s2 = __shfl_xor(ssum, off);
        float q0 = __shfl_xor(o0, off);
        float q1 = __shfl_xor(o1, off);
        float q2 = __shfl_xor(o2, off);
        float q3 = __shfl_xor(o3, off);
        float M = fmaxf(m, m2);
        float ca = (m  > -INFINITY) ? __expf(m - M) : 0.f;
        float cb = (m2 > -INFINITY) ? __expf(m2 - M) : 0.f;
        ssum = ssum * ca + s2 * cb;
        o0 = o0 * ca + q0 * cb;
        o1 = o1 * ca + q1 * cb;
        o2 = o2 * ca + q2 * cb;
        o3 = o3 * ca + q3 * cb;
        m = M;
    }

    float inv = 1.f / (ssum + 1e-16f);
    float4 res;
    res.x = o0 * inv; res.y = o1 * inv; res.z = o2 * inv; res.w = o3 * inv;
    if (AMODE == 1) {
        res.x = (res.x > 0.f) ? res.x : expm1f(res.x);
        res.y = (res.y > 0.f) ? res.y : expm1f(res.y);
        res.z = (res.z > 0.f) ? res.z : expm1f(res.z);
        res.w = (res.w > 0.f) ? res.w : expm1f(res.w);
    } else {
        res.x = (res.x > 0.f) ? res.x : 32.f * expm1f(res.x);
        res.y = (res.y > 0.f) ? res.y : 32.f * expm1f(res.y);
        res.z = (res.z > 0.f) ? res.z : 32.f * expm1f(res.z);
        res.w = (res.w > 0.f) ? res.w : 32.f * expm1f(res.w);
    }
    if (grp == 0) *(float4*)&out[(size_t)wid * F + fl * 4] = res;
}

// ---------------- launcher ----------------

extern "C" void kernel_launch(void* const* d_in, const int* in_sizes, int n_in,
                              void* d_out, int out_size, void* d_ws, size_t ws_size,
                              hipStream_t stream) {
    const float* x    = (const float*)d_in[0];
    const int*   ei   = (const int*)d_in[1];
    const float* Wl1  = (const float*)d_in[2];
    const float* Wr1  = (const float*)d_in[3];
    const float* att1 = (const float*)d_in[4];
    const float* Wl2  = (const float*)d_in[5];
    const float* Wr2  = (const float*)d_in[6];
    const float* att2 = (const float*)d_in[7];
    const float* Wl3  = (const float*)d_in[8];
    const float* Wr3  = (const float*)d_in[9];
    const float* att3 = (const float*)d_in[10];
    const float* Wl4  = (const float*)d_in[11];
    const float* Wr4  = (const float*)d_in[12];
    const float* att4 = (const float*)d_in[13];

    const int N = in_sizes[0] / 128;
    const int E = in_sizes[1] / 2;
    const int* src = ei;
    const int* dst = ei + E;

    char* w = (char*)d_ws;
    size_t off = 0;
    auto take = [&](size_t bytes) -> void* {
        void* p = w + off;
        off = (off + bytes + 255) & ~(size_t)255;
        return p;
    };
    int* deg      = (int*)take((size_t)N * 4);
    int* cursor   = (int*)take((size_t)N * 4);
    int* incl     = (int*)take((size_t)N * 4);
    int* bsums    = (int*)take(4096);
    int* rowstart = (int*)take((size_t)(N + 1) * 4);
    int* csr_src  = (int*)take((size_t)E * 4);
    float* xl = (float*)take((size_t)N * 64 * 4);
    float* xr = (float*)take((size_t)N * 64 * 4);
    float* hA = (float*)take((size_t)N * 64 * 4);
    float* hB = (float*)take((size_t)N * 64 * 4);
    // packed weights: per mat, 2 parts of NT*NK*512 ushorts
    unsigned short* pWl1 = (unsigned short*)take(2 * 4 * 4 * 512 * 2);
    unsigned short* pWr1 = (unsigned short*)take(2 * 4 * 4 * 512 * 2);
    unsigned short* pWl2 = (unsigned short*)take(2 * 4 * 2 * 512 * 2);
    unsigned short* pWr2 = (unsigned short*)take(2 * 4 * 2 * 512 * 2);
    unsigned short* pWl3 = (unsigned short*)take(2 * 4 * 2 * 512 * 2);
    unsigned short* pWr3 = (unsigned short*)take(2 * 4 * 2 * 512 * 2);
    unsigned short* pWl4 = (unsigned short*)take(2 * 2 * 2 * 512 * 2);
    unsigned short* pWr4 = (unsigned short*)take(2 * 2 * 2 * 512 * 2);
    float* outf = (float*)d_out;

    hipMemsetAsync(deg, 0, (size_t)N * 4, stream);
    hipMemsetAsync(cursor, 0, (size_t)N * 4, stream);

    // weight prepack (tiny)
    prepack_kernel<<<(2 * 4 * 4 * 512 + 255) / 256, 256, 0, stream>>>(Wl1, Wr1, pWl1, pWr1, 128, 64);
    prepack_kernel<<<(2 * 4 * 2 * 512 + 255) / 256, 256, 0, stream>>>(Wl2, Wr2, pWl2, pWr2, 64, 64);
    prepack_kernel<<<(2 * 4 * 2 * 512 + 255) / 256, 256, 0, stream>>>(Wl3, Wr3, pWl3, pWr3, 64, 64);
    prepack_kernel<<<(2 * 2 * 2 * 512 + 255) / 256, 256, 0, stream>>>(Wl4, Wr4, pWl4, pWr4, 64, 32);

    int ebl = (E + 255) / 256;
    hist_kernel<<<ebl, 256, 0, stream>>>(dst, deg, E);

    int nsb = (N + SCAN_B - 1) / SCAN_B;
    scan1_kernel<<<nsb, SCAN_B, 0, stream>>>(deg, incl, bsums, N);
    scan2_kernel<<<1, 1024, 0, stream>>>(bsums, nsb);
    scan3_kernel<<<nsb, SCAN_B, 0, stream>>>(incl, deg, bsums, rowstart, N, E);

    int np = (N + NXCD - 1) / NXCD;
    int nchunk = (E + SCAT_CHUNK - 1) / SCAT_CHUNK;
    scatter_kernel<<<nchunk * NXCD, 256, 0, stream>>>(src, dst, rowstart, cursor, csr_src, E, np);

    int aggbl = (N * 64 + 255) / 256;
    int pblk = (N + 63) / 64;

    // layer 1: 128 -> 64, ELU
    proj_mfma_kernel<128, 64><<<pblk, 256, 0, stream>>>(x, pWl1, pWr1, xl, xr, N);
    agg_kernel<64, 1><<<aggbl, 256, 0, stream>>>(xl, xr, att1, rowstart, csr_src, hA, N);

    // layer 2: 64 -> 64, ELU
    proj_mfma_kernel<64, 64><<<pblk, 256, 0, stream>>>(hA, pWl2, pWr2, xl, xr, N);
    agg_kernel<64, 1><<<aggbl, 256, 0, stream>>>(xl, xr, att2, rowstart, csr_src, hB, N);

    // layer 3: 64 -> 64, ELU
    proj_mfma_kernel<64, 64><<<pblk, 256, 0, stream>>>(hB, pWl3, pWr3, xl, xr, N);
    agg_kernel<64, 1><<<aggbl, 256, 0, stream>>>(xl, xr, att3, rowstart, csr_src, hA, N);

    // layer 4: 64 -> 32, final ELU (alpha = 32)
    proj_mfma_kernel<64, 32><<<pblk, 256, 0, stream>>>(hA, pWl4, pWr4, xl, xr, N);
    agg_kernel<32, 2><<<aggbl, 256, 0, stream>>>(xl, xr, att4, rowstart, csr_src, outf, N);
}

// Round 5
// 415.113 us; speedup vs baseline: 2.7117x; 1.2047x over previous
//
#include <hip/hip_runtime.h>
#include <math.h>

typedef __attribute__((ext_vector_type(8))) short bf16x8;
typedef __attribute__((ext_vector_type(4))) float f32x4;

#define BSHIFT 7               // 128 nodes per bucket
#define CH 8192                // edges per block in bucket hist/scatter

__device__ inline unsigned short f32_to_bf16_bits(float f) {
    unsigned int u = __float_as_uint(f);
    unsigned int r = (u + 0x7fffu + ((u >> 16) & 1u)) >> 16;   // RNE
    return (unsigned short)r;
}
__device__ inline float bf16_bits_to_f32(unsigned short h) {
    return __uint_as_float(((unsigned int)h) << 16);
}

// ================= 2-level bucket CSR build =================
// buckets of 128 nodes; per-XCD-replicated counters (blockIdx&7) to avoid
// cross-XCD atomic line ping-pong.

__global__ __launch_bounds__(256) void bucket_hist(
    const int* __restrict__ dst, int* __restrict__ bcnt8, int E, int nb, int nbp)
{
    __shared__ int h[1024];
    for (int i = threadIdx.x; i < nb; i += 256) h[i] = 0;
    __syncthreads();
    int e0 = blockIdx.x * CH, e1 = min(e0 + CH, E);
    for (int e = e0 + (int)threadIdx.x; e < e1; e += 256)
        atomicAdd(&h[dst[e] >> BSHIFT], 1);
    __syncthreads();
    int* mycnt = bcnt8 + (blockIdx.x & 7) * nbp;
    for (int b = threadIdx.x; b < nb; b += 256) {
        int c = h[b];
        if (c) atomicAdd(&mycnt[b], c);
    }
}

// one block, 1024 threads: scan bucket totals; emit per-copy cursors.
__global__ void bucket_scan(const int* __restrict__ bcnt8, int* __restrict__ bbase,
                            int* __restrict__ bcur8, int* __restrict__ rowstart,
                            int nb, int nbp, int E, int N)
{
    __shared__ int sh[1024];
    int t = threadIdx.x;
    int g8[8];
    int tot = 0;
#pragma unroll
    for (int g = 0; g < 8; ++g) {
        int c = (t < nb) ? bcnt8[g * nbp + t] : 0;
        g8[g] = c; tot += c;
    }
    sh[t] = tot;
    __syncthreads();
    for (int d = 1; d < 1024; d <<= 1) {
        int a = (t >= d) ? sh[t - d] : 0;
        __syncthreads();
        sh[t] += a;
        __syncthreads();
    }
    int base = sh[t] - tot;   // exclusive
    if (t <= nb) bbase[t] = base;      // bbase[nb] == E
    if (t < nb) {
        int run = base;
#pragma unroll
        for (int g = 0; g < 8; ++g) { bcur8[g * nbp + t] = run; run += g8[g]; }
    }
    if (t == 0) rowstart[N] = E;
}

__global__ __launch_bounds__(256) void bucket_scatter(
    const int* __restrict__ src, const int* __restrict__ dst,
    int* __restrict__ bcur8, int2* __restrict__ pairs, int E, int nb, int nbp)
{
    __shared__ int h[1024];
    for (int i = threadIdx.x; i < nb; i += 256) h[i] = 0;
    __syncthreads();
    int e0 = blockIdx.x * CH, e1 = min(e0 + CH, E);
    for (int e = e0 + (int)threadIdx.x; e < e1; e += 256)
        atomicAdd(&h[dst[e] >> BSHIFT], 1);
    __syncthreads();
    int* mycur = bcur8 + (blockIdx.x & 7) * nbp;
    for (int b = threadIdx.x; b < nb; b += 256) {
        int c = h[b];
        if (c) h[b] = atomicAdd(&mycur[b], c);   // h[b] becomes running cursor
    }
    __syncthreads();
    for (int e = e0 + (int)threadIdx.x; e < e1; e += 256) {
        int d = dst[e];
        int pos = atomicAdd(&h[d >> BSHIFT], 1);
        pairs[pos] = make_int2(src[e], d);
    }
}

// one block per bucket: local hist + scan -> rowstart, then local scatter.
__global__ __launch_bounds__(256) void bucket_finalize(
    const int2* __restrict__ pairs, const int* __restrict__ bbase,
    int* __restrict__ rowstart, int* __restrict__ csr_src, int N)
{
    __shared__ int h[128];
    __shared__ int sh[256];
    int b = blockIdx.x;
    int p0 = bbase[b], p1 = bbase[b + 1];
    int t = threadIdx.x;
    if (t < 128) h[t] = 0;
    __syncthreads();
    for (int e = p0 + t; e < p1; e += 256)
        atomicAdd(&h[pairs[e].y & 127], 1);
    __syncthreads();
    int v = (t < 128) ? h[t] : 0;
    sh[t] = v;
    __syncthreads();
    for (int d = 1; d < 256; d <<= 1) {
        int a = (t >= d) ? sh[t - d] : 0;
        __syncthreads();
        sh[t] += a;
        __syncthreads();
    }
    if (t < 128) {
        int off = sh[t] - v;     // exclusive
        int node = (b << BSHIFT) + t;
        if (node < N) rowstart[node] = p0 + off;
        h[t] = p0 + off;         // cursor
    }
    __syncthreads();
    for (int e = p0 + t; e < p1; e += 256) {
        int2 pr = pairs[e];
        int pos = atomicAdd(&h[pr.y & 127], 1);
        csr_src[pos] = pr.x;
    }
}

// ================= weight prepack (unchanged) =================

__global__ void prepack_kernel(const float* __restrict__ Wl, const float* __restrict__ Wr,
                               unsigned short* __restrict__ pWl, unsigned short* __restrict__ pWr,
                               int FIN, int FOUT) {
    int NT = FOUT >> 4, NK = FIN >> 5;
    int part = NT * NK * 512;
    int i = blockIdx.x * blockDim.x + threadIdx.x;
    int m = i / part;
    if (m >= 2) return;
    int ii = i - m * part;
    int j = ii & 7;
    int lane = (ii >> 3) & 63;
    int rest = ii >> 9;
    int ks = rest % NK;
    int t = rest / NK;
    int k = ks * 32 + (lane >> 4) * 8 + j;
    int c = t * 16 + (lane & 15);
    const float* W = m ? Wr : Wl;
    unsigned short* P = m ? pWr : pWl;
    float w = W[(size_t)k * FOUT + c];
    unsigned short hi = f32_to_bf16_bits(w);
    unsigned short lo = f32_to_bf16_bits(w - bf16_bits_to_f32(hi));
    P[ii] = hi;
    P[part + ii] = lo;
}

// ================= MFMA projection + att-dot epilogue =================
// xl = x@Wl, xr = x@Wr (bf16 hi/lo 3-product split, f32 accum)
// epilogue also emits dl[n] = xl[n].att, dr[n] = xr[n].att

template<int FIN, int FOUT>
__global__ __launch_bounds__(256) void proj_mfma_kernel(
    const float* __restrict__ x,
    const unsigned short* __restrict__ pWl, const unsigned short* __restrict__ pWr,
    const float* __restrict__ att,
    float* __restrict__ xl, float* __restrict__ xr,
    float* __restrict__ dl, float* __restrict__ dr, int n)
{
    constexpr int NT = FOUT >> 4;
    constexpr int NK = FIN >> 5;
    constexpr int PART = NT * NK * 512;
    const int wave = threadIdx.x >> 6;
    const int lane = threadIdx.x & 63;
    const int row0 = blockIdx.x * 64 + wave * 16;
    int arow = row0 + (lane & 15);
    if (arow >= n) arow = n - 1;
    const int khalf = lane >> 4;

    f32x4 accl[NT], accr[NT];
#pragma unroll
    for (int t = 0; t < NT; ++t) {
        accl[t] = (f32x4){0.f, 0.f, 0.f, 0.f};
        accr[t] = (f32x4){0.f, 0.f, 0.f, 0.f};
    }

    const float* xrow = x + (size_t)arow * FIN + khalf * 8;
#pragma unroll
    for (int ks = 0; ks < NK; ++ks) {
        float4 a0 = *(const float4*)(xrow + ks * 32);
        float4 a1 = *(const float4*)(xrow + ks * 32 + 4);
        float av[8] = {a0.x, a0.y, a0.z, a0.w, a1.x, a1.y, a1.z, a1.w};
        bf16x8 ah, al;
#pragma unroll
        for (int j = 0; j < 8; ++j) {
            unsigned short h = f32_to_bf16_bits(av[j]);
            ah[j] = (short)h;
            al[j] = (short)f32_to_bf16_bits(av[j] - bf16_bits_to_f32(h));
        }
#pragma unroll
        for (int t = 0; t < NT; ++t) {
            const unsigned short* bpl = pWl + ((size_t)(t * NK + ks) * 64 + lane) * 8;
            bf16x8 bh  = *(const bf16x8*)bpl;
            bf16x8 blo = *(const bf16x8*)(bpl + PART);
            accl[t] = __builtin_amdgcn_mfma_f32_16x16x32_bf16(ah, bh,  accl[t], 0, 0, 0);
            accl[t] = __builtin_amdgcn_mfma_f32_16x16x32_bf16(ah, blo, accl[t], 0, 0, 0);
            accl[t] = __builtin_amdgcn_mfma_f32_16x16x32_bf16(al, bh,  accl[t], 0, 0, 0);
            const unsigned short* bpr = pWr + ((size_t)(t * NK + ks) * 64 + lane) * 8;
            bh  = *(const bf16x8*)bpr;
            blo = *(const bf16x8*)(bpr + PART);
            accr[t] = __builtin_amdgcn_mfma_f32_16x16x32_bf16(ah, bh,  accr[t], 0, 0, 0);
            accr[t] = __builtin_amdgcn_mfma_f32_16x16x32_bf16(ah, blo, accr[t], 0, 0, 0);
            accr[t] = __builtin_amdgcn_mfma_f32_16x16x32_bf16(al, bh,  accr[t], 0, 0, 0);
        }
    }

    const int orow0 = row0 + khalf * 4;
    const int colb = lane & 15;
    float attc[NT];
#pragma unroll
    for (int t = 0; t < NT; ++t) attc[t] = att[t * 16 + colb];

#pragma unroll
    for (int t = 0; t < NT; ++t) {
        int col = t * 16 + colb;
#pragma unroll
        for (int r = 0; r < 4; ++r) {
            int rr = orow0 + r;
            if (rr < n) {
                xl[(size_t)rr * FOUT + col] = accl[t][r];
                xr[(size_t)rr * FOUT + col] = accr[t][r];
            }
        }
    }
    // att-dot epilogue: reduce over the 16 lanes of this khalf group
#pragma unroll
    for (int r = 0; r < 4; ++r) {
        float pl = 0.f, pr = 0.f;
#pragma unroll
        for (int t = 0; t < NT; ++t) { pl += accl[t][r] * attc[t]; pr += accr[t][r] * attc[t]; }
#pragma unroll
        for (int off = 1; off < 16; off <<= 1) {
            pl += __shfl_xor(pl, off);
            pr += __shfl_xor(pr, off);
        }
        int rr = orow0 + r;
        if (colb == 0 && rr < n) { dl[rr] = pl; dr[rr] = pr; }
    }
}

// ================= per-dst online-softmax aggregation =================
// score = 0.6*(dl[src]+dr[dst]) + 0.4*sum(att*|xl[src]+xr[dst]|)
// (identity: lrelu(s,0.2) = 0.6*s + 0.4*|s|, applied inside the att-dot)
// defer-max: rescale only when p > m + 8 (exp(p-m) <= e^8, f32-safe).

template<int F, int AMODE>
__global__ __launch_bounds__(256) void agg_kernel(
    const float* __restrict__ xl, const float* __restrict__ xr, const float* __restrict__ att,
    const float* __restrict__ dl, const float* __restrict__ dr,
    const int* __restrict__ rowstart, const int* __restrict__ csr_src,
    float* __restrict__ out, int n)
{
    constexpr int LPE = F / 4;
    constexpr int GRP = 64 / LPE;
    constexpr int LSH = (F == 64) ? 6 : 5;

    int wid = (blockIdx.x * blockDim.x + threadIdx.x) >> 6;
    int lane = threadIdx.x & 63;
    if (wid >= n) return;
    int grp = lane / LPE;
    int fl  = lane % LPE;

    float4 xrv  = *(const float4*)&xr[((unsigned)wid << LSH) + fl * 4];
    float4 attv = *(const float4*)&att[fl * 4];
    float cdr = 0.6f * dr[wid];

    int s0 = rowstart[wid], s1 = rowstart[wid + 1];
    int niter = (s1 - s0 + GRP - 1) / GRP;
    int s1c = max(s1 - 1, 0);

    float m = -1e30f, mth = -1e30f, ssum = 0.f;
    float o0 = 0.f, o1 = 0.f, o2 = 0.f, o3 = 0.f;

    int idx = s0 + grp;
    int sv = csr_src[min(idx, s1c)];

    for (int it = 0; it < niter; ++it) {
        unsigned xoff = ((unsigned)sv << LSH) + fl * 4;
        float4 xv = *(const float4*)(xl + xoff);
        float dlv = dl[sv];

        int nidx = idx + GRP;
        int nsv = csr_src[min(nidx, s1c)];
        bool valid = idx < s1;

        float e0 = xv.x + xrv.x;
        float e1 = xv.y + xrv.y;
        float e2 = xv.z + xrv.z;
        float e3 = xv.w + xrv.w;
        float t = attv.x * fabsf(e0) + attv.y * fabsf(e1)
                + attv.z * fabsf(e2) + attv.w * fabsf(e3);
#pragma unroll
        for (int off = 1; off < LPE; off <<= 1) t += __shfl_xor(t, off);

        float p = 0.6f * dlv + cdr + 0.4f * t;
        p = valid ? p : -1e30f;

        if (p > mth) {              // rare after first iteration
            float c = __expf(m - p);
            ssum *= c; o0 *= c; o1 *= c; o2 *= c; o3 *= c;
            m = p; mth = p + 8.0f;
        }
        float w = __expf(p - m);
        ssum += w;
        o0 += w * xv.x; o1 += w * xv.y; o2 += w * xv.z; o3 += w * xv.w;
        idx = nidx; sv = nsv;
    }

    // merge GRP group-states (butterfly)
#pragma unroll
    for (int off = LPE; off < 64; off <<= 1) {
        float m2 = __shfl_xor(m, off);
        float s2 = __shfl_xor(ssum, off);
        float q0 = __shfl_xor(o0, off);
        float q1 = __shfl_xor(o1, off);
        float q2 = __shfl_xor(o2, off);
        float q3 = __shfl_xor(o3, off);
        float M = fmaxf(m, m2);
        float ca = __expf(m - M);
        float cb = __expf(m2 - M);
        ssum = ssum * ca + s2 * cb;
        o0 = o0 * ca + q0 * cb;
        o1 = o1 * ca + q1 * cb;
        o2 = o2 * ca + q2 * cb;
        o3 = o3 * ca + q3 * cb;
        m = M;
    }

    float inv = 1.f / (ssum + 1e-16f);
    float4 res;
    res.x = o0 * inv; res.y = o1 * inv; res.z = o2 * inv; res.w = o3 * inv;
    if (AMODE == 1) {
        res.x = (res.x > 0.f) ? res.x : expm1f(res.x);
        res.y = (res.y > 0.f) ? res.y : expm1f(res.y);
        res.z = (res.z > 0.f) ? res.z : expm1f(res.z);
        res.w = (res.w > 0.f) ? res.w : expm1f(res.w);
    } else {
        res.x = (res.x > 0.f) ? res.x : 32.f * expm1f(res.x);
        res.y = (res.y > 0.f) ? res.y : 32.f * expm1f(res.y);
        res.z = (res.z > 0.f) ? res.z : 32.f * expm1f(res.z);
        res.w = (res.w > 0.f) ? res.w : 32.f * expm1f(res.w);
    }
    if (grp == 0) *(float4*)&out[((unsigned)wid << LSH) + fl * 4] = res;
}

// ================= launcher =================

extern "C" void kernel_launch(void* const* d_in, const int* in_sizes, int n_in,
                              void* d_out, int out_size, void* d_ws, size_t ws_size,
                              hipStream_t stream) {
    const float* x    = (const float*)d_in[0];
    const int*   ei   = (const int*)d_in[1];
    const float* Wl1  = (const float*)d_in[2];
    const float* Wr1  = (const float*)d_in[3];
    const float* att1 = (const float*)d_in[4];
    const float* Wl2  = (const float*)d_in[5];
    const float* Wr2  = (const float*)d_in[6];
    const float* att2 = (const float*)d_in[7];
    const float* Wl3  = (const float*)d_in[8];
    const float* Wr3  = (const float*)d_in[9];
    const float* att3 = (const float*)d_in[10];
    const float* Wl4  = (const float*)d_in[11];
    const float* Wr4  = (const float*)d_in[12];
    const float* att4 = (const float*)d_in[13];

    const int N = in_sizes[0] / 128;
    const int E = in_sizes[1] / 2;
    const int* src = ei;
    const int* dst = ei + E;

    const int nb  = (N + 127) >> BSHIFT;   // buckets
    const int nbp = (nb + 15) & ~15;       // padded stride for 8 copies

    char* w = (char*)d_ws;
    size_t off = 0;
    auto take = [&](size_t bytes) -> void* {
        void* p = w + off;
        off = (off + bytes + 255) & ~(size_t)255;
        return p;
    };
    int* bcnt8    = (int*)take((size_t)8 * nbp * 4);
    int* bcur8    = (int*)take((size_t)8 * nbp * 4);
    int* bbase    = (int*)take((size_t)(nb + 1) * 4);
    int* rowstart = (int*)take((size_t)(N + 1) * 4);
    int* csr_src  = (int*)take((size_t)E * 4);
    float* dl = (float*)take((size_t)N * 4);
    float* dr = (float*)take((size_t)N * 4);
    float* xl = (float*)take((size_t)N * 64 * 4);
    float* xr = (float*)take((size_t)N * 64 * 4);
    float* hA = (float*)take((size_t)N * 64 * 4);
    float* hB = (float*)take((size_t)N * 64 * 4);
    unsigned short* pWl1 = (unsigned short*)take(2 * 4 * 4 * 512 * 2);
    unsigned short* pWr1 = (unsigned short*)take(2 * 4 * 4 * 512 * 2);
    unsigned short* pWl2 = (unsigned short*)take(2 * 4 * 2 * 512 * 2);
    unsigned short* pWr2 = (unsigned short*)take(2 * 4 * 2 * 512 * 2);
    unsigned short* pWl3 = (unsigned short*)take(2 * 4 * 2 * 512 * 2);
    unsigned short* pWr3 = (unsigned short*)take(2 * 4 * 2 * 512 * 2);
    unsigned short* pWl4 = (unsigned short*)take(2 * 2 * 2 * 512 * 2);
    unsigned short* pWr4 = (unsigned short*)take(2 * 2 * 2 * 512 * 2);
    // pairs (E int2 = 12.8MB) aliases hA (25.6MB): consumed by bucket_finalize
    // before layer-1 agg writes hA (stream-ordered).
    int2* pairs = (int2*)hA;
    float* outf = (float*)d_out;

    hipMemsetAsync(bcnt8, 0, (size_t)8 * nbp * 4, stream);

    // weight prepack (tiny)
    prepack_kernel<<<(2 * 4 * 4 * 512 + 255) / 256, 256, 0, stream>>>(Wl1, Wr1, pWl1, pWr1, 128, 64);
    prepack_kernel<<<(2 * 4 * 2 * 512 + 255) / 256, 256, 0, stream>>>(Wl2, Wr2, pWl2, pWr2, 64, 64);
    prepack_kernel<<<(2 * 4 * 2 * 512 + 255) / 256, 256, 0, stream>>>(Wl3, Wr3, pWl3, pWr3, 64, 64);
    prepack_kernel<<<(2 * 2 * 2 * 512 + 255) / 256, 256, 0, stream>>>(Wl4, Wr4, pWl4, pWr4, 64, 32);

    // CSR build
    int kgrid = (E + CH - 1) / CH;
    bucket_hist<<<kgrid, 256, 0, stream>>>(dst, bcnt8, E, nb, nbp);
    bucket_scan<<<1, 1024, 0, stream>>>(bcnt8, bbase, bcur8, rowstart, nb, nbp, E, N);
    bucket_scatter<<<kgrid, 256, 0, stream>>>(src, dst, bcur8, pairs, E, nb, nbp);
    bucket_finalize<<<nb, 256, 0, stream>>>(pairs, bbase, rowstart, csr_src, N);

    int aggbl = (N * 64 + 255) / 256;
    int pblk = (N + 63) / 64;

    // layer 1: 128 -> 64, ELU
    proj_mfma_kernel<128, 64><<<pblk, 256, 0, stream>>>(x, pWl1, pWr1, att1, xl, xr, dl, dr, N);
    agg_kernel<64, 1><<<aggbl, 256, 0, stream>>>(xl, xr, att1, dl, dr, rowstart, csr_src, hA, N);

    // layer 2: 64 -> 64, ELU
    proj_mfma_kernel<64, 64><<<pblk, 256, 0, stream>>>(hA, pWl2, pWr2, att2, xl, xr, dl, dr, N);
    agg_kernel<64, 1><<<aggbl, 256, 0, stream>>>(xl, xr, att2, dl, dr, rowstart, csr_src, hB, N);

    // layer 3: 64 -> 64, ELU
    proj_mfma_kernel<64, 64><<<pblk, 256, 0, stream>>>(hB, pWl3, pWr3, att3, xl, xr, dl, dr, N);
    agg_kernel<64, 1><<<aggbl, 256, 0, stream>>>(xl, xr, att3, dl, dr, rowstart, csr_src, hA, N);

    // layer 4: 64 -> 32, final ELU (alpha = 32)
    proj_mfma_kernel<64, 32><<<pblk, 256, 0, stream>>>(hA, pWl4, pWr4, att4, xl, xr, dl, dr, N);
    agg_kernel<32, 2><<<aggbl, 256, 0, stream>>>(xl, xr, att4, dl, dr, rowstart, csr_src, outf, N);
}

// Round 6
// 398.994 us; speedup vs baseline: 2.8212x; 1.0404x over previous
//
#include <hip/hip_runtime.h>
#include <math.h>

typedef __attribute__((ext_vector_type(8))) short bf16x8;
typedef __attribute__((ext_vector_type(4))) float f32x4;

#define BSHIFT 7               // 128 nodes per bucket
#define CH 8192                // edges per block in bucket hist/scatter

__device__ inline unsigned short f32_to_bf16_bits(float f) {
    unsigned int u = __float_as_uint(f);
    unsigned int r = (u + 0x7fffu + ((u >> 16) & 1u)) >> 16;   // RNE
    return (unsigned short)r;
}
__device__ inline float bf16_bits_to_f32(unsigned short h) {
    return __uint_as_float(((unsigned int)h) << 16);
}

// single-instruction lane xor-swizzle add (BitMode: (xor<<10)|0x1F)
#define SWZ_ADD(t, imm) \
    t += __int_as_float(__builtin_amdgcn_ds_swizzle(__float_as_int(t), imm))

// ================= 2-level bucket CSR build =================

__global__ __launch_bounds__(256) void bucket_hist(
    const int* __restrict__ dst, int* __restrict__ bcnt8, int E, int nb, int nbp)
{
    __shared__ int h[1024];
    for (int i = threadIdx.x; i < nb; i += 256) h[i] = 0;
    __syncthreads();
    int e0 = blockIdx.x * CH, e1 = min(e0 + CH, E);
    for (int e = e0 + (int)threadIdx.x; e < e1; e += 256)
        atomicAdd(&h[dst[e] >> BSHIFT], 1);
    __syncthreads();
    int* mycnt = bcnt8 + (blockIdx.x & 7) * nbp;
    for (int b = threadIdx.x; b < nb; b += 256) {
        int c = h[b];
        if (c) atomicAdd(&mycnt[b], c);
    }
}

__global__ void bucket_scan(const int* __restrict__ bcnt8, int* __restrict__ bbase,
                            int* __restrict__ bcur8, int* __restrict__ rowstart,
                            int nb, int nbp, int E, int N)
{
    __shared__ int sh[1024];
    int t = threadIdx.x;
    int g8[8];
    int tot = 0;
#pragma unroll
    for (int g = 0; g < 8; ++g) {
        int c = (t < nb) ? bcnt8[g * nbp + t] : 0;
        g8[g] = c; tot += c;
    }
    sh[t] = tot;
    __syncthreads();
    for (int d = 1; d < 1024; d <<= 1) {
        int a = (t >= d) ? sh[t - d] : 0;
        __syncthreads();
        sh[t] += a;
        __syncthreads();
    }
    int base = sh[t] - tot;   // exclusive
    if (t <= nb) bbase[t] = base;
    if (t < nb) {
        int run = base;
#pragma unroll
        for (int g = 0; g < 8; ++g) { bcur8[g * nbp + t] = run; run += g8[g]; }
    }
    if (t == 0) rowstart[N] = E;
}

__global__ __launch_bounds__(256) void bucket_scatter(
    const int* __restrict__ src, const int* __restrict__ dst,
    int* __restrict__ bcur8, int2* __restrict__ pairs, int E, int nb, int nbp)
{
    __shared__ int h[1024];
    for (int i = threadIdx.x; i < nb; i += 256) h[i] = 0;
    __syncthreads();
    int e0 = blockIdx.x * CH, e1 = min(e0 + CH, E);
    for (int e = e0 + (int)threadIdx.x; e < e1; e += 256)
        atomicAdd(&h[dst[e] >> BSHIFT], 1);
    __syncthreads();
    int* mycur = bcur8 + (blockIdx.x & 7) * nbp;
    for (int b = threadIdx.x; b < nb; b += 256) {
        int c = h[b];
        if (c) h[b] = atomicAdd(&mycur[b], c);
    }
    __syncthreads();
    for (int e = e0 + (int)threadIdx.x; e < e1; e += 256) {
        int d = dst[e];
        int pos = atomicAdd(&h[d >> BSHIFT], 1);
        pairs[pos] = make_int2(src[e], d);
    }
}

__global__ __launch_bounds__(256) void bucket_finalize(
    const int2* __restrict__ pairs, const int* __restrict__ bbase,
    int* __restrict__ rowstart, int* __restrict__ csr_src, int N)
{
    __shared__ int h[128];
    __shared__ int sh[256];
    int b = blockIdx.x;
    int p0 = bbase[b], p1 = bbase[b + 1];
    int t = threadIdx.x;
    if (t < 128) h[t] = 0;
    __syncthreads();
    for (int e = p0 + t; e < p1; e += 256)
        atomicAdd(&h[pairs[e].y & 127], 1);
    __syncthreads();
    int v = (t < 128) ? h[t] : 0;
    sh[t] = v;
    __syncthreads();
    for (int d = 1; d < 256; d <<= 1) {
        int a = (t >= d) ? sh[t - d] : 0;
        __syncthreads();
        sh[t] += a;
        __syncthreads();
    }
    if (t < 128) {
        int off = sh[t] - v;
        int node = (b << BSHIFT) + t;
        if (node < N) rowstart[node] = p0 + off;
        h[t] = p0 + off;
    }
    __syncthreads();
    for (int e = p0 + t; e < p1; e += 256) {
        int2 pr = pairs[e];
        int pos = atomicAdd(&h[pr.y & 127], 1);
        csr_src[pos] = pr.x;
    }
}

// ================= weight prepack =================

__global__ void prepack_kernel(const float* __restrict__ Wl, const float* __restrict__ Wr,
                               unsigned short* __restrict__ pWl, unsigned short* __restrict__ pWr,
                               int FIN, int FOUT) {
    int NT = FOUT >> 4, NK = FIN >> 5;
    int part = NT * NK * 512;
    int i = blockIdx.x * blockDim.x + threadIdx.x;
    int m = i / part;
    if (m >= 2) return;
    int ii = i - m * part;
    int j = ii & 7;
    int lane = (ii >> 3) & 63;
    int rest = ii >> 9;
    int ks = rest % NK;
    int t = rest / NK;
    int k = ks * 32 + (lane >> 4) * 8 + j;
    int c = t * 16 + (lane & 15);
    const float* W = m ? Wr : Wl;
    unsigned short* P = m ? pWr : pWl;
    float w = W[(size_t)k * FOUT + c];
    unsigned short hi = f32_to_bf16_bits(w);
    unsigned short lo = f32_to_bf16_bits(w - bf16_bits_to_f32(hi));
    P[ii] = hi;
    P[part + ii] = lo;
}

// ================= MFMA projection + att-dot epilogue =================

template<int FIN, int FOUT>
__global__ __launch_bounds__(256) void proj_mfma_kernel(
    const float* __restrict__ x,
    const unsigned short* __restrict__ pWl, const unsigned short* __restrict__ pWr,
    const float* __restrict__ att,
    float* __restrict__ xl, float* __restrict__ xr,
    float* __restrict__ dl, float* __restrict__ dr, int n)
{
    constexpr int NT = FOUT >> 4;
    constexpr int NK = FIN >> 5;
    constexpr int PART = NT * NK * 512;
    const int wave = threadIdx.x >> 6;
    const int lane = threadIdx.x & 63;
    const int row0 = blockIdx.x * 64 + wave * 16;
    int arow = row0 + (lane & 15);
    if (arow >= n) arow = n - 1;
    const int khalf = lane >> 4;

    f32x4 accl[NT], accr[NT];
#pragma unroll
    for (int t = 0; t < NT; ++t) {
        accl[t] = (f32x4){0.f, 0.f, 0.f, 0.f};
        accr[t] = (f32x4){0.f, 0.f, 0.f, 0.f};
    }

    const float* xrow = x + (size_t)arow * FIN + khalf * 8;
#pragma unroll
    for (int ks = 0; ks < NK; ++ks) {
        float4 a0 = *(const float4*)(xrow + ks * 32);
        float4 a1 = *(const float4*)(xrow + ks * 32 + 4);
        float av[8] = {a0.x, a0.y, a0.z, a0.w, a1.x, a1.y, a1.z, a1.w};
        bf16x8 ah, al;
#pragma unroll
        for (int j = 0; j < 8; ++j) {
            unsigned short h = f32_to_bf16_bits(av[j]);
            ah[j] = (short)h;
            al[j] = (short)f32_to_bf16_bits(av[j] - bf16_bits_to_f32(h));
        }
#pragma unroll
        for (int t = 0; t < NT; ++t) {
            const unsigned short* bpl = pWl + ((size_t)(t * NK + ks) * 64 + lane) * 8;
            bf16x8 bh  = *(const bf16x8*)bpl;
            bf16x8 blo = *(const bf16x8*)(bpl + PART);
            accl[t] = __builtin_amdgcn_mfma_f32_16x16x32_bf16(ah, bh,  accl[t], 0, 0, 0);
            accl[t] = __builtin_amdgcn_mfma_f32_16x16x32_bf16(ah, blo, accl[t], 0, 0, 0);
            accl[t] = __builtin_amdgcn_mfma_f32_16x16x32_bf16(al, bh,  accl[t], 0, 0, 0);
            const unsigned short* bpr = pWr + ((size_t)(t * NK + ks) * 64 + lane) * 8;
            bh  = *(const bf16x8*)bpr;
            blo = *(const bf16x8*)(bpr + PART);
            accr[t] = __builtin_amdgcn_mfma_f32_16x16x32_bf16(ah, bh,  accr[t], 0, 0, 0);
            accr[t] = __builtin_amdgcn_mfma_f32_16x16x32_bf16(ah, blo, accr[t], 0, 0, 0);
            accr[t] = __builtin_amdgcn_mfma_f32_16x16x32_bf16(al, bh,  accr[t], 0, 0, 0);
        }
    }

    const int orow0 = row0 + khalf * 4;
    const int colb = lane & 15;
    float attc[NT];
#pragma unroll
    for (int t = 0; t < NT; ++t) attc[t] = att[t * 16 + colb];

#pragma unroll
    for (int t = 0; t < NT; ++t) {
        int col = t * 16 + colb;
#pragma unroll
        for (int r = 0; r < 4; ++r) {
            int rr = orow0 + r;
            if (rr < n) {
                xl[(size_t)rr * FOUT + col] = accl[t][r];
                xr[(size_t)rr * FOUT + col] = accr[t][r];
            }
        }
    }
#pragma unroll
    for (int r = 0; r < 4; ++r) {
        float pl = 0.f, pr = 0.f;
#pragma unroll
        for (int t = 0; t < NT; ++t) { pl += accl[t][r] * attc[t]; pr += accr[t][r] * attc[t]; }
#pragma unroll
        for (int off = 1; off < 16; off <<= 1) {
            pl += __shfl_xor(pl, off);
            pr += __shfl_xor(pr, off);
        }
        int rr = orow0 + r;
        if (colb == 0 && rr < n) { dl[rr] = pl; dr[rr] = pr; }
    }
}

// ================= per-dst online-softmax aggregation =================
// Group-per-node: LPE = F/4 lanes own ONE node each; NPG = 64/LPE nodes/wave.
// No cross-group merge, no validity masking. Score via
// att.lrelu(s) = 0.6*(dl[src]+dr[dst]) + 0.4*sum(att*|s|); defer-max (thr 8).
// Group score-reduce: single-instruction ds_swizzle xor-butterfly.

template<int F, int AMODE>
__global__ __launch_bounds__(256) void agg_kernel(
    const float* __restrict__ xl, const float* __restrict__ xr, const float* __restrict__ att,
    const float* __restrict__ dl, const float* __restrict__ dr,
    const int* __restrict__ rowstart, const int* __restrict__ csr_src,
    float* __restrict__ out, int n, int E)
{
    constexpr int LPE = F / 4;            // lanes per node
    constexpr int LSH = (F == 64) ? 6 : 5;
    constexpr int NPG = 64 / LPE;         // nodes per wave

    int wv  = (blockIdx.x * blockDim.x + threadIdx.x) >> 6;
    int lane = threadIdx.x & 63;
    int grp = lane / LPE;
    int fl  = lane % LPE;
    int node = wv * NPG + grp;
    bool act = node < n;
    int nc = act ? node : 0;

    float4 xrv  = *(const float4*)&xr[((unsigned)nc << LSH) + fl * 4];
    float4 attv = *(const float4*)&att[fl * 4];
    float cdr = 0.6f * dr[nc];

    int s0 = rowstart[nc];
    int s1 = act ? rowstart[nc + 1] : s0;

    float m = -1e30f, mth = -1e30f, ssum = 0.f;
    float o0 = 0.f, o1 = 0.f, o2 = 0.f, o3 = 0.f;

    int i = s0;
    int sv = csr_src[min(i, E - 1)];
    while (i < s1) {                      // group-uniform; divergence only across groups
        unsigned xoff = ((unsigned)sv << LSH) + fl * 4;
        float4 xv = *(const float4*)(xl + xoff);
        float dlv = dl[sv];
        int ni = i + 1;
        int nsv = csr_src[min(ni, E - 1)];

        float t = attv.x * fabsf(xv.x + xrv.x)
                + attv.y * fabsf(xv.y + xrv.y)
                + attv.z * fabsf(xv.z + xrv.z)
                + attv.w * fabsf(xv.w + xrv.w);
        SWZ_ADD(t, 0x041F);               // xor 1
        SWZ_ADD(t, 0x081F);               // xor 2
        SWZ_ADD(t, 0x101F);               // xor 4
        if (LPE == 16) SWZ_ADD(t, 0x201F);// xor 8

        float p = 0.6f * dlv + cdr + 0.4f * t;

        if (p > mth) {                    // rare after first edge
            float c = __expf(m - p);
            ssum *= c; o0 *= c; o1 *= c; o2 *= c; o3 *= c;
            m = p; mth = p + 8.0f;
        }
        float w = __expf(p - m);
        ssum += w;
        o0 += w * xv.x; o1 += w * xv.y; o2 += w * xv.z; o3 += w * xv.w;
        i = ni; sv = nsv;
    }

    float inv = 1.f / (ssum + 1e-16f);
    float4 res;
    res.x = o0 * inv; res.y = o1 * inv; res.z = o2 * inv; res.w = o3 * inv;
    if (AMODE == 1) {
        res.x = (res.x > 0.f) ? res.x : expm1f(res.x);
        res.y = (res.y > 0.f) ? res.y : expm1f(res.y);
        res.z = (res.z > 0.f) ? res.z : expm1f(res.z);
        res.w = (res.w > 0.f) ? res.w : expm1f(res.w);
    } else {
        res.x = (res.x > 0.f) ? res.x : 32.f * expm1f(res.x);
        res.y = (res.y > 0.f) ? res.y : 32.f * expm1f(res.y);
        res.z = (res.z > 0.f) ? res.z : 32.f * expm1f(res.z);
        res.w = (res.w > 0.f) ? res.w : 32.f * expm1f(res.w);
    }
    if (act) *(float4*)&out[((unsigned)node << LSH) + fl * 4] = res;
}

// ================= launcher =================

extern "C" void kernel_launch(void* const* d_in, const int* in_sizes, int n_in,
                              void* d_out, int out_size, void* d_ws, size_t ws_size,
                              hipStream_t stream) {
    const float* x    = (const float*)d_in[0];
    const int*   ei   = (const int*)d_in[1];
    const float* Wl1  = (const float*)d_in[2];
    const float* Wr1  = (const float*)d_in[3];
    const float* att1 = (const float*)d_in[4];
    const float* Wl2  = (const float*)d_in[5];
    const float* Wr2  = (const float*)d_in[6];
    const float* att2 = (const float*)d_in[7];
    const float* Wl3  = (const float*)d_in[8];
    const float* Wr3  = (const float*)d_in[9];
    const float* att3 = (const float*)d_in[10];
    const float* Wl4  = (const float*)d_in[11];
    const float* Wr4  = (const float*)d_in[12];
    const float* att4 = (const float*)d_in[13];

    const int N = in_sizes[0] / 128;
    const int E = in_sizes[1] / 2;
    const int* src = ei;
    const int* dst = ei + E;

    const int nb  = (N + 127) >> BSHIFT;
    const int nbp = (nb + 15) & ~15;

    char* w = (char*)d_ws;
    size_t off = 0;
    auto take = [&](size_t bytes) -> void* {
        void* p = w + off;
        off = (off + bytes + 255) & ~(size_t)255;
        return p;
    };
    int* bcnt8    = (int*)take((size_t)8 * nbp * 4);
    int* bcur8    = (int*)take((size_t)8 * nbp * 4);
    int* bbase    = (int*)take((size_t)(nb + 1) * 4);
    int* rowstart = (int*)take((size_t)(N + 1) * 4);
    int* csr_src  = (int*)take((size_t)E * 4);
    float* dl = (float*)take((size_t)N * 4);
    float* dr = (float*)take((size_t)N * 4);
    float* xl = (float*)take((size_t)N * 64 * 4);
    float* xr = (float*)take((size_t)N * 64 * 4);
    float* hA = (float*)take((size_t)N * 64 * 4);
    float* hB = (float*)take((size_t)N * 64 * 4);
    unsigned short* pWl1 = (unsigned short*)take(2 * 4 * 4 * 512 * 2);
    unsigned short* pWr1 = (unsigned short*)take(2 * 4 * 4 * 512 * 2);
    unsigned short* pWl2 = (unsigned short*)take(2 * 4 * 2 * 512 * 2);
    unsigned short* pWr2 = (unsigned short*)take(2 * 4 * 2 * 512 * 2);
    unsigned short* pWl3 = (unsigned short*)take(2 * 4 * 2 * 512 * 2);
    unsigned short* pWr3 = (unsigned short*)take(2 * 4 * 2 * 512 * 2);
    unsigned short* pWl4 = (unsigned short*)take(2 * 2 * 2 * 512 * 2);
    unsigned short* pWr4 = (unsigned short*)take(2 * 2 * 2 * 512 * 2);
    int2* pairs = (int2*)hA;   // aliases hA; consumed before layer-1 agg writes hA
    float* outf = (float*)d_out;

    hipMemsetAsync(bcnt8, 0, (size_t)8 * nbp * 4, stream);

    prepack_kernel<<<(2 * 4 * 4 * 512 + 255) / 256, 256, 0, stream>>>(Wl1, Wr1, pWl1, pWr1, 128, 64);
    prepack_kernel<<<(2 * 4 * 2 * 512 + 255) / 256, 256, 0, stream>>>(Wl2, Wr2, pWl2, pWr2, 64, 64);
    prepack_kernel<<<(2 * 4 * 2 * 512 + 255) / 256, 256, 0, stream>>>(Wl3, Wr3, pWl3, pWr3, 64, 64);
    prepack_kernel<<<(2 * 2 * 2 * 512 + 255) / 256, 256, 0, stream>>>(Wl4, Wr4, pWl4, pWr4, 64, 32);

    int kgrid = (E + CH - 1) / CH;
    bucket_hist<<<kgrid, 256, 0, stream>>>(dst, bcnt8, E, nb, nbp);
    bucket_scan<<<1, 1024, 0, stream>>>(bcnt8, bbase, bcur8, rowstart, nb, nbp, E, N);
    bucket_scatter<<<kgrid, 256, 0, stream>>>(src, dst, bcur8, pairs, E, nb, nbp);
    bucket_finalize<<<nb, 256, 0, stream>>>(pairs, bbase, rowstart, csr_src, N);

    int pblk = (N + 63) / 64;
    int agg64 = (N + 15) / 16;    // 4 waves/block, 4 nodes/wave
    int agg32 = (N + 31) / 32;    // 4 waves/block, 8 nodes/wave

    // layer 1: 128 -> 64, ELU
    proj_mfma_kernel<128, 64><<<pblk, 256, 0, stream>>>(x, pWl1, pWr1, att1, xl, xr, dl, dr, N);
    agg_kernel<64, 1><<<agg64, 256, 0, stream>>>(xl, xr, att1, dl, dr, rowstart, csr_src, hA, N, E);

    // layer 2: 64 -> 64, ELU
    proj_mfma_kernel<64, 64><<<pblk, 256, 0, stream>>>(hA, pWl2, pWr2, att2, xl, xr, dl, dr, N);
    agg_kernel<64, 1><<<agg64, 256, 0, stream>>>(xl, xr, att2, dl, dr, rowstart, csr_src, hB, N, E);

    // layer 3: 64 -> 64, ELU
    proj_mfma_kernel<64, 64><<<pblk, 256, 0, stream>>>(hB, pWl3, pWr3, att3, xl, xr, dl, dr, N);
    agg_kernel<64, 1><<<agg64, 256, 0, stream>>>(xl, xr, att3, dl, dr, rowstart, csr_src, hA, N, E);

    // layer 4: 64 -> 32, final ELU (alpha = 32)
    proj_mfma_kernel<64, 32><<<pblk, 256, 0, stream>>>(hA, pWl4, pWr4, att4, xl, xr, dl, dr, N);
    agg_kernel<32, 2><<<agg32, 256, 0, stream>>>(xl, xr, att4, dl, dr, rowstart, csr_src, outf, N, E);
}